// Round 9
// baseline (143.103 us; speedup 1.0000x reference)
//
#include <hip/hip_runtime.h>

namespace {

typedef short    v4s __attribute__((ext_vector_type(4)));
typedef float    v4f __attribute__((ext_vector_type(4)));
typedef float    f4  __attribute__((ext_vector_type(4)));
typedef unsigned u2  __attribute__((ext_vector_type(2)));

constexpr int Tt = 512;
constexpr int Dd = 64;
constexpr float LN2 = 0.69314718055994530942f;

// RNE bf16 pack (bit-twiddle; off critical path)
__device__ __forceinline__ unsigned pk_bf16(float a, float b) {
  unsigned ua = __float_as_uint(a), ub = __float_as_uint(b);
  ua += 0x7fffu + ((ua >> 16) & 1u);
  ub += 0x7fffu + ((ub >> 16) & 1u);
  return (ua >> 16) | (ub & 0xffff0000u);
}
// 1-instruction truncation pack via v_perm_b32
__device__ __forceinline__ unsigned pktrunc(float lo, float hi) {
  return __builtin_amdgcn_perm(__float_as_uint(hi), __float_as_uint(lo), 0x07060302u);
}
__device__ __forceinline__ v4s mk4(unsigned lo, unsigned hi) {
  union { unsigned u[2]; v4s s; } z;
  z.u[0] = lo; z.u[1] = hi; return z.s;
}
__device__ __forceinline__ float bf_lo(unsigned u) { return __uint_as_float(u << 16); }
__device__ __forceinline__ float bf_hi(unsigned u) { return __uint_as_float(u & 0xffff0000u); }

__device__ __forceinline__ v4f mfma16(v4s a, v4s b, v4f c) {
  return __builtin_amdgcn_mfma_f32_16x16x16bf16_1k(a, b, c, 0, 0, 0);
}
__device__ __forceinline__ float fexp2(float x) {
#if __has_builtin(__builtin_amdgcn_exp2f)
  return __builtin_amdgcn_exp2f(x);
#else
  return exp2f(x);
#endif
}

// E LDS index (u2 = 8B units) for (t_local in [0,64), x, wblk)
__device__ __forceinline__ int eidx(int tl, int x, int wblk) {
  return tl * 64 + x * 4 + (wblk ^ (x >> 2));
}

__global__ __launch_bounds__(64, 1) void fhmm_fwd(
    const float* __restrict__ seq,     // [B, T, D]
    const int*   __restrict__ lengths, // [B]
    const float* __restrict__ pw,      // [16,16]
    const float* __restrict__ px,      // [16,16]
    const float* __restrict__ py,      // [16,16,64]
    float*       __restrict__ out,     // [B]
    u2*          __restrict__ wsdif)   // [16*4*64] B-frag table (shared, 32 KB)
{
  const int b = blockIdx.x;
  const int l = threadIdx.x;
  const int g = l >> 4;
  const int x = l & 15;

  __shared__ u2    Elds[64 * 64];  // ONE chunk: 64 t × 256 s, bf16(E+base) pairs
  __shared__ float Mbuf[512];      // global-t max shifts

  // ---------- init: write dif B-frag table to ws; per-state base ----------
  // Entry [(st*4+c)*64 + l]: lane(g,x)'s v4s pair for B[k=4g+i][n=x],
  // i.e. dif[st*16+x][16c+4g+i], i=0..3, as 2 packed u32.
  float bfull[16];
#pragma unroll
  for (int st = 0; st < 16; ++st) {
    float part = 0.f;
#pragma unroll
    for (int c = 0; c < 4; ++c) {
      f4 p = *(const f4*)(py + (st * 16 + x) * 64 + c * 16 + g * 4);
      float q0 = __log2f(1.f - p.x), q1 = __log2f(1.f - p.y),
            q2 = __log2f(1.f - p.z), q3 = __log2f(1.f - p.w);
      part += (q0 + q1) + (q2 + q3);
      u2 wv;
      wv.x = pk_bf16(__log2f(p.x) - q0, __log2f(p.y) - q1);
      wv.y = pk_bf16(__log2f(p.z) - q2, __log2f(p.w) - q3);
      wsdif[(st * 4 + c) * 64 + l] = wv;   // all blocks write identical bytes
    }
    part += __shfl_xor(part, 16, 64);
    part += __shfl_xor(part, 32, 64);
    bfull[st] = part;   // base[st*16 + x]
  }

  v4s pwB, pxB;
  {
    const int r0 = (4 * g) * 16 + x;
    pwB = mk4(pk_bf16(pw[r0], pw[r0 + 16]), pk_bf16(pw[r0 + 32], pw[r0 + 48]));
    pxB = mk4(pk_bf16(px[r0], px[r0 + 16]), pk_bf16(px[r0 + 32], px[r0 + 48]));
  }
  const float p0w0 = pw[4 * g + 0], p0w1 = pw[4 * g + 1],
              p0w2 = pw[4 * g + 2], p0w3 = pw[4 * g + 3];
  const float px0 = px[x];

  const int len = lengths[b];
  const int nch = (len + 63) >> 6;
  const float* yb = seq + (size_t)b * (Tt * Dd);

  float acc = 0.f;
  v4f al = {0.f, 0.f, 0.f, 0.f};
  const v4f z4 = {0.f, 0.f, 0.f, 0.f};

#pragma unroll 1
  for (int ch = 0; ch < nch; ++ch) {
    const int tb = ch * 64;

    // ======== chunk GEMM: E'[t][s] = base[s] + sum_d y[t][d] dif[s][d] ========
    // All 16 y A-frags for the chunk (32 VGPR), loads issued back-to-back.
    v4s ya[4][4];
#pragma unroll
    for (int mt = 0; mt < 4; ++mt) {
      const float* yp = yb + (size_t)(tb + mt * 16 + x) * 64 + g * 4;
      f4 y0 = *(const f4*)(yp + 0);
      f4 y1 = *(const f4*)(yp + 16);
      f4 y2 = *(const f4*)(yp + 32);
      f4 y3 = *(const f4*)(yp + 48);
      ya[mt][0] = mk4(pk_bf16(y0.x, y0.y), pk_bf16(y0.z, y0.w));
      ya[mt][1] = mk4(pk_bf16(y1.x, y1.y), pk_bf16(y1.z, y1.w));
      ya[mt][2] = mk4(pk_bf16(y2.x, y2.y), pk_bf16(y2.z, y2.w));
      ya[mt][3] = mk4(pk_bf16(y3.x, y3.y), pk_bf16(y3.z, y3.w));
    }
    float mx[4][4];
#pragma unroll
    for (int mt = 0; mt < 4; ++mt)
#pragma unroll
      for (int id = 0; id < 4; ++id) mx[mt][id] = -1e30f;

#pragma unroll
    for (int q = 0; q < 4; ++q) {
      // B-frags for states 4q..4q+3 from the shared table (L2-resident)
      u2 Bq[4][4];
#pragma unroll
      for (int j = 0; j < 4; ++j)
#pragma unroll
        for (int c = 0; c < 4; ++c)
          Bq[j][c] = wsdif[((4 * q + j) * 4 + c) * 64 + l];

      const float b0 = bfull[4 * q + 0], b1 = bfull[4 * q + 1],
                  b2 = bfull[4 * q + 2], b3 = bfull[4 * q + 3];
#pragma unroll
      for (int mt = 0; mt < 4; ++mt) {
        v4f a0 = z4, a1 = z4, a2 = z4, a3 = z4;
#pragma unroll
        for (int c = 0; c < 4; ++c) {
          a0 = mfma16(ya[mt][c], mk4(Bq[0][c].x, Bq[0][c].y), a0);
          a1 = mfma16(ya[mt][c], mk4(Bq[1][c].x, Bq[1][c].y), a1);
          a2 = mfma16(ya[mt][c], mk4(Bq[2][c].x, Bq[2][c].y), a2);
          a3 = mfma16(ya[mt][c], mk4(Bq[3][c].x, Bq[3][c].y), a3);
        }
        // D layout: lane (g,x) reg id holds t = tb+mt*16+4g+id, col = x
#pragma unroll
        for (int id = 0; id < 4; ++id) {
          const float e0 = a0[id] + b0, e1 = a1[id] + b1,
                      e2 = a2[id] + b2, e3 = a3[id] + b3;
          u2 wv;
          wv.x = pk_bf16(e0, e1);
          wv.y = pk_bf16(e2, e3);
          Elds[eidx(mt * 16 + 4 * g + id, x, q)] = wv;
          const float mq = fmaxf(fmaxf(e0, e1), fmaxf(e2, e3));
          mx[mt][id] = fmaxf(mx[mt][id], mq);
        }
      }
    }
    // M'[t] = max_s E': reduce over the 16 x-lanes, write Mbuf
#pragma unroll
    for (int mt = 0; mt < 4; ++mt) {
#pragma unroll
      for (int o = 1; o <= 8; o <<= 1) {
        mx[mt][0] = fmaxf(mx[mt][0], __shfl_xor(mx[mt][0], o, 64));
        mx[mt][1] = fmaxf(mx[mt][1], __shfl_xor(mx[mt][1], o, 64));
        mx[mt][2] = fmaxf(mx[mt][2], __shfl_xor(mx[mt][2], o, 64));
        mx[mt][3] = fmaxf(mx[mt][3], __shfl_xor(mx[mt][3], o, 64));
      }
      const int t0 = tb + mt * 16;
      if (x == 0) Mbuf[t0 + 4 * g + 0] = mx[mt][0];
      if (x == 1) Mbuf[t0 + 4 * g + 1] = mx[mt][1];
      if (x == 2) Mbuf[t0 + 4 * g + 2] = mx[mt][2];
      if (x == 3) Mbuf[t0 + 4 * g + 3] = mx[mt][3];
    }

    __syncthreads();   // GEMM writes -> scan reads

    // ======== scan phase: steps t in [tb, te) ========
    const int te = (len < tb + 64) ? len : (tb + 64);
    int t = tb;
    u2 Ec = Elds[eidx(0, x, g)];
    float Mc = Mbuf[tb];

#define SCAN_STEP(PF)                                                       \
    {                                                                       \
      u2 En_ = Ec; float Mn_ = Mc;                                          \
      PF                                                                    \
      const float e0 = fexp2(bf_lo(Ec.x) - Mc);                             \
      const float e1 = fexp2(bf_hi(Ec.x) - Mc);                             \
      const float e2 = fexp2(bf_lo(Ec.y) - Mc);                             \
      const float e3 = fexp2(bf_hi(Ec.y) - Mc);                             \
      v4s a16 = mk4(pktrunc(al[0], al[1]), pktrunc(al[2], al[3]));          \
      v4f d1 = mfma16(a16, pwB, z4);                                        \
      v4s d16 = mk4(pktrunc(d1[0], d1[1]), pktrunc(d1[2], d1[3]));          \
      v4f d2 = mfma16(d16, pxB, z4);                                        \
      al[0] = d2[0] * e0; al[1] = d2[1] * e1;                               \
      al[2] = d2[2] * e2; al[3] = d2[3] * e3;                               \
      Ec = En_; Mc = Mn_;                                                   \
    }

#define RENORM                                                              \
    {                                                                       \
      float S = (al[0] + al[1]) + (al[2] + al[3]);                          \
      _Pragma("unroll")                                                     \
      for (int o = 1; o <= 32; o <<= 1) S += __shfl_xor(S, o, 64);          \
      S = fmaxf(S, 1e-35f);                                                 \
      const float r = __builtin_amdgcn_rcpf(S);                             \
      al[0] *= r; al[1] *= r; al[2] *= r; al[3] *= r;                       \
      acc += __log2f(S);                                                    \
    }

    if (ch == 0) {   // peel t = 0: alpha0 = prior * e
      const float e0 = fexp2(bf_lo(Ec.x) - Mc);
      const float e1 = fexp2(bf_hi(Ec.x) - Mc);
      const float e2 = fexp2(bf_lo(Ec.y) - Mc);
      const float e3 = fexp2(bf_hi(Ec.y) - Mc);
      al[0] = p0w0 * px0 * e0; al[1] = p0w1 * px0 * e1;
      al[2] = p0w2 * px0 * e2; al[3] = p0w3 * px0 * e3;
      t = 1;
      if (t < te) { Ec = Elds[eidx(1, x, g)]; Mc = Mbuf[1]; }
    }

    while (t < te && (t & 7)) {     // guarded entry until 8-aligned
      SCAN_STEP(
        if (t + 1 < te) { En_ = Elds[eidx((t + 1) & 63, x, g)]; Mn_ = Mbuf[t + 1]; })
      if ((t & 7) == 7) RENORM
      ++t;
    }
    while (t + 8 <= te) {           // fast path: 8-step groups
#pragma unroll
      for (int k = 0; k < 8; ++k) {
        const int tn = t + k + 1;
        SCAN_STEP(
          En_ = Elds[eidx(tn & 63, x, g)]; Mn_ = Mbuf[tn < 511 ? tn : 511];)
      }
      RENORM
      t += 8;
    }
    while (t < te) {                // guarded tail
      SCAN_STEP(
        if (t + 1 < te) { En_ = Elds[eidx((t + 1) & 63, x, g)]; Mn_ = Mbuf[t + 1]; })
      if ((t & 7) == 7) RENORM
      ++t;
    }
#undef SCAN_STEP
#undef RENORM

    __syncthreads();   // scan reads done -> next chunk GEMM may overwrite
  }

  // ---------- finalize ----------
  float S = (al[0] + al[1]) + (al[2] + al[3]);
#pragma unroll
  for (int o = 1; o <= 32; o <<= 1) S += __shfl_xor(S, o, 64);
  S = fmaxf(S, 1e-35f);
  acc += __log2f(S);

  float msum = 0.f;
  for (int t2 = l; t2 < len; t2 += 64) msum += Mbuf[t2];
#pragma unroll
  for (int o = 1; o <= 32; o <<= 1) msum += __shfl_xor(msum, o, 64);

  if (l == 0) out[b] = LN2 * (acc + msum);
}

} // namespace

extern "C" void kernel_launch(void* const* d_in, const int* in_sizes, int n_in,
                              void* d_out, int out_size, void* d_ws, size_t ws_size,
                              hipStream_t stream) {
  const float* seq     = (const float*)d_in[0];
  const int*   lengths = (const int*)d_in[1];
  const float* pw      = (const float*)d_in[2];
  const float* px      = (const float*)d_in[3];
  const float* py      = (const float*)d_in[4];
  float*       out     = (float*)d_out;
  u2*          wsdif   = (u2*)d_ws;    // 32 KB shared B-frag table

  hipLaunchKernelGGL(fhmm_fwd, dim3(1024), dim3(64), 0, stream,
                     seq, lengths, pw, px, py, out, wsdif);
}

// Round 10
// 125.560 us; speedup vs baseline: 1.1397x; 1.1397x over previous
//
#include <hip/hip_runtime.h>

namespace {

typedef short    v4s __attribute__((ext_vector_type(4)));
typedef float    v4f __attribute__((ext_vector_type(4)));
typedef float    f4  __attribute__((ext_vector_type(4)));
typedef unsigned u2  __attribute__((ext_vector_type(2)));

constexpr int Tt = 512;
constexpr int Dd = 64;
constexpr float LN2 = 0.69314718055994530942f;

// RNE bf16 pack (bit-twiddle; off critical path)
__device__ __forceinline__ unsigned pk_bf16(float a, float b) {
  unsigned ua = __float_as_uint(a), ub = __float_as_uint(b);
  ua += 0x7fffu + ((ua >> 16) & 1u);
  ub += 0x7fffu + ((ub >> 16) & 1u);
  return (ua >> 16) | (ub & 0xffff0000u);
}
// 1-instruction truncation pack via v_perm_b32
__device__ __forceinline__ unsigned pktrunc(float lo, float hi) {
  return __builtin_amdgcn_perm(__float_as_uint(hi), __float_as_uint(lo), 0x07060302u);
}
__device__ __forceinline__ v4s mk4(unsigned lo, unsigned hi) {
  union { unsigned u[2]; v4s s; } z;
  z.u[0] = lo; z.u[1] = hi; return z.s;
}
__device__ __forceinline__ float bf_lo(unsigned u) { return __uint_as_float(u << 16); }
__device__ __forceinline__ float bf_hi(unsigned u) { return __uint_as_float(u & 0xffff0000u); }

__device__ __forceinline__ v4f mfma16(v4s a, v4s b, v4f c) {
  return __builtin_amdgcn_mfma_f32_16x16x16bf16_1k(a, b, c, 0, 0, 0);
}
__device__ __forceinline__ float fexp2(float x) {
#if __has_builtin(__builtin_amdgcn_exp2f)
  return __builtin_amdgcn_exp2f(x);
#else
  return exp2f(x);
#endif
}

// E LDS index (u2 = 8B units) for (t_local in [0,64), x, wblk)
__device__ __forceinline__ int eidx(int tl, int x, int wblk) {
  return tl * 64 + x * 4 + (wblk ^ (x >> 2));
}

__global__ __launch_bounds__(64, 1) void fhmm_fwd(
    const float* __restrict__ seq,     // [B, T, D]
    const int*   __restrict__ lengths, // [B]
    const float* __restrict__ pw,      // [16,16]
    const float* __restrict__ px,      // [16,16]
    const float* __restrict__ py,      // [16,16,64]
    float*       __restrict__ out,     // [B]
    u2*          __restrict__ wsdif)   // [16*4*64] B-frag table (shared, 32 KB)
{
  const int b = blockIdx.x;
  const int l = threadIdx.x;
  const int g = l >> 4;
  const int x = l & 15;

  __shared__ u2    Elds[64 * 64];          // ONE chunk: 64 t × 256 s, bf16 pairs
  __shared__ float Mbuf[512];              // global-t max shifts
  __shared__ __align__(16) float MxT[64 * 20];  // per-chunk M transpose pad

  // ---------- init: write dif B-frag table to ws; per-state base ----------
  float bfull[16];
#pragma unroll
  for (int st = 0; st < 16; ++st) {
    float part = 0.f;
#pragma unroll
    for (int c = 0; c < 4; ++c) {
      f4 p = *(const f4*)(py + (st * 16 + x) * 64 + c * 16 + g * 4);
      float q0 = __log2f(1.f - p.x), q1 = __log2f(1.f - p.y),
            q2 = __log2f(1.f - p.z), q3 = __log2f(1.f - p.w);
      part += (q0 + q1) + (q2 + q3);
      u2 wv;
      wv.x = pk_bf16(__log2f(p.x) - q0, __log2f(p.y) - q1);
      wv.y = pk_bf16(__log2f(p.z) - q2, __log2f(p.w) - q3);
      wsdif[(st * 4 + c) * 64 + l] = wv;   // all blocks write identical bytes
    }
    part += __shfl_xor(part, 16, 64);
    part += __shfl_xor(part, 32, 64);
    bfull[st] = part;   // base[st*16 + x]
  }

  v4s pwB, pxB;
  {
    const int r0 = (4 * g) * 16 + x;
    pwB = mk4(pk_bf16(pw[r0], pw[r0 + 16]), pk_bf16(pw[r0 + 32], pw[r0 + 48]));
    pxB = mk4(pk_bf16(px[r0], px[r0 + 16]), pk_bf16(px[r0 + 32], px[r0 + 48]));
  }
  const float p0w0 = pw[4 * g + 0], p0w1 = pw[4 * g + 1],
              p0w2 = pw[4 * g + 2], p0w3 = pw[4 * g + 3];
  const float px0 = px[x];

  const int len = lengths[b];
  const int nch = (len + 63) >> 6;
  const float* yb = seq + (size_t)b * (Tt * Dd);

  float acc = 0.f;
  v4f al = {0.f, 0.f, 0.f, 0.f};
  const v4f z4 = {0.f, 0.f, 0.f, 0.f};

#pragma unroll 1
  for (int ch = 0; ch < nch; ++ch) {
    const int tb = ch * 64;

    // ======== chunk GEMM: E'[t][s] = base[s] + sum_d y[t][d] dif[s][d] ========
    v4s ya[4][4];
#pragma unroll
    for (int mt = 0; mt < 4; ++mt) {
      const float* yp = yb + (size_t)(tb + mt * 16 + x) * 64 + g * 4;
      f4 y0 = *(const f4*)(yp + 0);
      f4 y1 = *(const f4*)(yp + 16);
      f4 y2 = *(const f4*)(yp + 32);
      f4 y3 = *(const f4*)(yp + 48);
      ya[mt][0] = mk4(pk_bf16(y0.x, y0.y), pk_bf16(y0.z, y0.w));
      ya[mt][1] = mk4(pk_bf16(y1.x, y1.y), pk_bf16(y1.z, y1.w));
      ya[mt][2] = mk4(pk_bf16(y2.x, y2.y), pk_bf16(y2.z, y2.w));
      ya[mt][3] = mk4(pk_bf16(y3.x, y3.y), pk_bf16(y3.z, y3.w));
    }
    float mx[4][4];
#pragma unroll
    for (int mt = 0; mt < 4; ++mt)
#pragma unroll
      for (int id = 0; id < 4; ++id) mx[mt][id] = -1e30f;

#pragma unroll
    for (int q = 0; q < 4; ++q) {
      u2 Bq[4][4];
#pragma unroll
      for (int j = 0; j < 4; ++j)
#pragma unroll
        for (int c = 0; c < 4; ++c)
          Bq[j][c] = wsdif[((4 * q + j) * 4 + c) * 64 + l];

      const float b0 = bfull[4 * q + 0], b1 = bfull[4 * q + 1],
                  b2 = bfull[4 * q + 2], b3 = bfull[4 * q + 3];
#pragma unroll
      for (int mt = 0; mt < 4; ++mt) {
        v4f a0 = z4, a1 = z4, a2 = z4, a3 = z4;
#pragma unroll
        for (int c = 0; c < 4; ++c) {
          a0 = mfma16(ya[mt][c], mk4(Bq[0][c].x, Bq[0][c].y), a0);
          a1 = mfma16(ya[mt][c], mk4(Bq[1][c].x, Bq[1][c].y), a1);
          a2 = mfma16(ya[mt][c], mk4(Bq[2][c].x, Bq[2][c].y), a2);
          a3 = mfma16(ya[mt][c], mk4(Bq[3][c].x, Bq[3][c].y), a3);
        }
#pragma unroll
        for (int id = 0; id < 4; ++id) {
          const float e0 = a0[id] + b0, e1 = a1[id] + b1,
                      e2 = a2[id] + b2, e3 = a3[id] + b3;
          u2 wv;
          wv.x = pk_bf16(e0, e1);
          wv.y = pk_bf16(e2, e3);
          Elds[eidx(mt * 16 + 4 * g + id, x, q)] = wv;
          const float mq = fmaxf(fmaxf(e0, e1), fmaxf(e2, e3));
          mx[mt][id] = fmaxf(mx[mt][id], mq);
        }
      }
    }
    // M'[t] = max_s E' via LDS transpose (no cross-lane shuffle chains)
#pragma unroll
    for (int mt = 0; mt < 4; ++mt)
#pragma unroll
      for (int id = 0; id < 4; ++id)
        MxT[(mt * 16 + 4 * g + id) * 20 + x] = mx[mt][id];
    __syncthreads();
    {
      const f4* row = (const f4*)&MxT[l * 20];
      f4 r0 = row[0], r1 = row[1], r2 = row[2], r3 = row[3];
      const float m01 = fmaxf(fmaxf(r0.x, r0.y), fmaxf(r0.z, r0.w));
      const float m23 = fmaxf(fmaxf(r1.x, r1.y), fmaxf(r1.z, r1.w));
      const float m45 = fmaxf(fmaxf(r2.x, r2.y), fmaxf(r2.z, r2.w));
      const float m67 = fmaxf(fmaxf(r3.x, r3.y), fmaxf(r3.z, r3.w));
      Mbuf[tb + l] = fmaxf(fmaxf(m01, m23), fmaxf(m45, m67));
    }

    __syncthreads();   // GEMM + M writes -> scan reads

    // ======== scan phase: steps t in [tb, te) ========
    const int te = (len < tb + 64) ? len : (tb + 64);
    int t = tb;
    u2 Ec = Elds[eidx(0, x, g)];
    float Mc = Mbuf[tb];

#define SCAN_STEP(PF)                                                       \
    {                                                                       \
      u2 En_ = Ec; float Mn_ = Mc;                                          \
      PF                                                                    \
      const float e0 = fexp2(bf_lo(Ec.x) - Mc);                             \
      const float e1 = fexp2(bf_hi(Ec.x) - Mc);                             \
      const float e2 = fexp2(bf_lo(Ec.y) - Mc);                             \
      const float e3 = fexp2(bf_hi(Ec.y) - Mc);                             \
      v4s a16 = mk4(pktrunc(al[0], al[1]), pktrunc(al[2], al[3]));          \
      v4f d1 = mfma16(a16, pwB, z4);                                        \
      v4s d16 = mk4(pktrunc(d1[0], d1[1]), pktrunc(d1[2], d1[3]));          \
      v4f d2 = mfma16(d16, pxB, z4);                                        \
      al[0] = d2[0] * e0; al[1] = d2[1] * e1;                               \
      al[2] = d2[2] * e2; al[3] = d2[3] * e3;                               \
      Ec = En_; Mc = Mn_;                                                   \
    }

#define RENORM                                                              \
    {                                                                       \
      float S = (al[0] + al[1]) + (al[2] + al[3]);                          \
      _Pragma("unroll")                                                     \
      for (int o = 1; o <= 32; o <<= 1) S += __shfl_xor(S, o, 64);          \
      S = fmaxf(S, 1e-35f);                                                 \
      const float r = __builtin_amdgcn_rcpf(S);                             \
      al[0] *= r; al[1] *= r; al[2] *= r; al[3] *= r;                       \
      acc += __log2f(S);                                                    \
    }

    if (ch == 0) {   // peel t = 0: alpha0 = prior * e
      const float e0 = fexp2(bf_lo(Ec.x) - Mc);
      const float e1 = fexp2(bf_hi(Ec.x) - Mc);
      const float e2 = fexp2(bf_lo(Ec.y) - Mc);
      const float e3 = fexp2(bf_hi(Ec.y) - Mc);
      al[0] = p0w0 * px0 * e0; al[1] = p0w1 * px0 * e1;
      al[2] = p0w2 * px0 * e2; al[3] = p0w3 * px0 * e3;
      t = 1;
      if (t < te) { Ec = Elds[eidx(1, x, g)]; Mc = Mbuf[1]; }
    }

    while (t < te && (t & 7)) {     // guarded entry until 8-aligned
      SCAN_STEP(
        if (t + 1 < te) { En_ = Elds[eidx((t + 1) & 63, x, g)]; Mn_ = Mbuf[t + 1]; })
      if ((t & 7) == 7) RENORM
      ++t;
    }

    // fast path: 8-step groups, depth-2 prefetch, software-pipelined renorm
    const int ng = (te - t) >> 3;
    if (ng > 0) {
      u2 E1 = Elds[eidx((t + 1) & 63, x, g)];
      float M1 = Mbuf[t + 1];
      float snap = 0.f, Sready = 1.0f, rdy = 1.0f;
#pragma unroll 1
      for (int gi = 0; gi < ng; ++gi) {
#pragma unroll
        for (int k = 0; k < 8; ++k) {
          const int tpf = t + k + 2;
          u2 E2 = Elds[eidx(tpf & 63, x, g)];          // 2-deep prefetch
          float M2 = Mbuf[tpf < 511 ? tpf : 511];      // (unused if tpf >= te)
          float e0 = fexp2(bf_lo(Ec.x) - Mc);
          float e1 = fexp2(bf_hi(Ec.x) - Mc);
          float e2 = fexp2(bf_lo(Ec.y) - Mc);
          float e3 = fexp2(bf_hi(Ec.y) - Mc);
          if (k == 0) {            // apply previous group's renorm via e (off chain)
            e0 *= rdy; e1 *= rdy; e2 *= rdy; e3 *= rdy;
            acc += __log2f(Sready);
          }
          v4s a16 = mk4(pktrunc(al[0], al[1]), pktrunc(al[2], al[3]));
          v4f d1 = mfma16(a16, pwB, z4);
          v4s d16 = mk4(pktrunc(d1[0], d1[1]), pktrunc(d1[2], d1[3]));
          v4f d2 = mfma16(d16, pxB, z4);
          al[0] = d2[0] * e0; al[1] = d2[1] * e1;
          al[2] = d2[2] * e2; al[3] = d2[3] * e3;
          if (k == 0) snap = (al[0] + al[1]) + (al[2] + al[3]);  // snapshot
          if (k >= 1 && k <= 6)                                   // 1 hop/step
            snap += __shfl_xor(snap, 1 << (k - 1), 64);
          if (k == 7) {                                           // factor ready
            Sready = fmaxf(snap, 1e-35f);
            rdy = __builtin_amdgcn_rcpf(Sready);
          }
          Ec = E1; Mc = M1; E1 = E2; M1 = M2;
        }
        t += 8;
      }
      // flush the last group's pending renorm
      acc += __log2f(Sready);
      al[0] *= rdy; al[1] *= rdy; al[2] *= rdy; al[3] *= rdy;
    }

    while (t < te) {                // guarded tail (final chunk only)
      SCAN_STEP(
        if (t + 1 < te) { En_ = Elds[eidx((t + 1) & 63, x, g)]; Mn_ = Mbuf[t + 1]; })
      if ((t & 7) == 7) RENORM
      ++t;
    }
#undef SCAN_STEP
#undef RENORM

    __syncthreads();   // scan reads done -> next chunk GEMM may overwrite
  }

  // ---------- finalize ----------
  float S = (al[0] + al[1]) + (al[2] + al[3]);
#pragma unroll
  for (int o = 1; o <= 32; o <<= 1) S += __shfl_xor(S, o, 64);
  S = fmaxf(S, 1e-35f);
  acc += __log2f(S);

  float msum = 0.f;
  for (int t2 = l; t2 < len; t2 += 64) msum += Mbuf[t2];
#pragma unroll
  for (int o = 1; o <= 32; o <<= 1) msum += __shfl_xor(msum, o, 64);

  if (l == 0) out[b] = LN2 * (acc + msum);
}

} // namespace

extern "C" void kernel_launch(void* const* d_in, const int* in_sizes, int n_in,
                              void* d_out, int out_size, void* d_ws, size_t ws_size,
                              hipStream_t stream) {
  const float* seq     = (const float*)d_in[0];
  const int*   lengths = (const int*)d_in[1];
  const float* pw      = (const float*)d_in[2];
  const float* px      = (const float*)d_in[3];
  const float* py      = (const float*)d_in[4];
  float*       out     = (float*)d_out;
  u2*          wsdif   = (u2*)d_ws;    // 32 KB shared B-frag table

  hipLaunchKernelGGL(fhmm_fwd, dim3(1024), dim3(64), 0, stream,
                     seq, lengths, pw, px, py, out, wsdif);
}